// Round 4
// baseline (509.522 us; speedup 1.0000x reference)
//
#include <hip/hip_runtime.h>
#include <math.h>

typedef short short8 __attribute__((ext_vector_type(8)));
typedef short short4v __attribute__((ext_vector_type(4)));
typedef float float4v __attribute__((ext_vector_type(4)));

// bf16 round-to-nearest-even from fp32, as raw bits in a short
__device__ __forceinline__ short f2bf(float f) {
    union { float f; unsigned u; } v; v.f = f;
    unsigned r = (v.u + 0x7FFFu + ((v.u >> 16) & 1u)) >> 16;
    return (short)r;
}

__device__ __forceinline__ void async16(const short* g, short* l) {
    __builtin_amdgcn_global_load_lds(
        (const __attribute__((address_space(1))) unsigned*)g,
        (__attribute__((address_space(3))) unsigned*)l, 16, 0, 0);
}

// ---------------- fused fp32->bf16 + sign-mask for q/k, PLUS weight cvt ----------------
// blocks [0,8192): q/k rows (4 rows/block). blocks [8192,8960): 3 weight matrices.
__global__ __launch_bounds__(256) void cvtmask_kernel(
    const float* __restrict__ q, const float* __restrict__ k,
    short* __restrict__ qb, short* __restrict__ kb,
    float* __restrict__ qm, float* __restrict__ km,
    const float* __restrict__ w0, const float* __restrict__ w1, const float* __restrict__ w2,
    short* __restrict__ d0, short* __restrict__ d1, short* __restrict__ d2) {
    int tid = threadIdx.x;
    if (blockIdx.x >= 8192) {
        int i = (blockIdx.x - 8192) * 256 + tid;   // 0 .. 3*65536
        int sel = i >> 16;
        int j = i & 65535;
        const float* src = (sel == 0) ? w0 : (sel == 1) ? w1 : w2;
        short* dst       = (sel == 0) ? d0 : (sel == 1) ? d1 : d2;
        float4v v = ((const float4v*)src)[j];
        short4v o;
        o[0] = f2bf(v[0]); o[1] = f2bf(v[1]); o[2] = f2bf(v[2]); o[3] = f2bf(v[3]);
        ((short4v*)dst)[j] = o;
        return;
    }
    int lane = tid & 63, wv = tid >> 6;
    int row = blockIdx.x * 4 + wv;
    const float* src; short* dst; float* msk; int r;
    if (row < 16384) { src = q; dst = qb; msk = qm; r = row; }
    else             { src = k; dst = kb; msk = km; r = row - 16384; }
    const float4v* p = (const float4v*)(src + (size_t)r * 512);
    float4v a = p[lane];
    float4v b = p[lane + 64];
    short4v o1, o2;
    o1[0] = f2bf(a[0]); o1[1] = f2bf(a[1]); o1[2] = f2bf(a[2]); o1[3] = f2bf(a[3]);
    o2[0] = f2bf(b[0]); o2[1] = f2bf(b[1]); o2[2] = f2bf(b[2]); o2[3] = f2bf(b[3]);
    short4v* d4 = (short4v*)(dst + (size_t)r * 512);
    d4[lane] = o1;
    d4[lane + 64] = o2;
    float s = fabsf(a[0]) + fabsf(a[1]) + fabsf(a[2]) + fabsf(a[3])
            + fabsf(b[0]) + fabsf(b[1]) + fabsf(b[2]) + fabsf(b[3]);
    #pragma unroll
    for (int off = 1; off < 64; off <<= 1) s += __shfl_xor(s, off, 64);
    if (lane == 0) msk[r] = (s > 0.f) ? 1.f : 0.f;
}

// ---------------- fused projection GEMM, 2-phase double-buffered (T3-minimum) ----------------
// Per K-step: barrier -> issue next-tile global_load_lds into alt buffer -> compute
// current buffer. Staging latency hides under the 32 MFMAs; ONE barrier per step
// (the next barrier drains the in-flight loads). LDS 64KB -> 2 blocks/CU.
__global__ __launch_bounds__(256) void proj_kernel(
    const short* __restrict__ Xq, const short* __restrict__ Xk,
    const short* __restrict__ Wqp, const short* __restrict__ Wkp, const short* __restrict__ Wvp,
    const float* __restrict__ bqp, const float* __restrict__ bkp, const float* __restrict__ bvp,
    short* __restrict__ Qo, short* __restrict__ Ko, short* __restrict__ Vo) {
    __shared__ short As[2][128 * 64];
    __shared__ short Bs[2][128 * 64];
    int z = blockIdx.z;
    const short* X    = (z == 0) ? Xq  : Xk;
    const short* W    = (z == 0) ? Wqp : (z == 1) ? Wkp : Wvp;
    const float* bias = (z == 0) ? bqp : (z == 1) ? bkp : bvp;
    short* out        = (z == 0) ? Qo  : (z == 1) ? Ko  : Vo;

    int tid = threadIdx.x;
    int lane = tid & 63, wv = tid >> 6;
    int col = lane & 15, quad = lane >> 4;
    int m0 = blockIdx.x * 128;
    int n0 = blockIdx.y * 128;
    int msub = (wv & 1) * 64, nsub = (wv >> 1) * 64;

    float4v acc[4][4];
    #pragma unroll
    for (int mt = 0; mt < 4; ++mt)
        #pragma unroll
        for (int nt = 0; nt < 4; ++nt) { acc[mt][nt][0]=0.f; acc[mt][nt][1]=0.f; acc[mt][nt][2]=0.f; acc[mt][nt][3]=0.f; }

    int rowS = tid >> 3;   // 0..31
    int seg  = tid & 7;    // 16B segment within a 128B row
    const short* gA = X + (size_t)(m0 + rowS) * 512 + seg * 8;
    const short* gB = W + (size_t)(n0 + rowS) * 512 + seg * 8;

    // prologue: stage step 0 into buffer 0
    #pragma unroll
    for (int j = 0; j < 4; ++j) {
        async16(gA + (size_t)(j * 32) * 512, &As[0][0] + (size_t)tid * 8 + j * 2048);
        async16(gB + (size_t)(j * 32) * 512, &Bs[0][0] + (size_t)tid * 8 + j * 2048);
    }

    for (int k0 = 0; k0 < 512; k0 += 64) {
        int cur = (k0 >> 6) & 1;
        __syncthreads();   // drains in-flight staging of `cur` (vmcnt) + all waves arrive
        if (k0 + 64 < 512) {
            int nxt = cur ^ 1;
            #pragma unroll
            for (int j = 0; j < 4; ++j) {
                async16(gA + (size_t)(j * 32) * 512 + k0 + 64, &As[nxt][0] + (size_t)tid * 8 + j * 2048);
                async16(gB + (size_t)(j * 32) * 512 + k0 + 64, &Bs[nxt][0] + (size_t)tid * 8 + j * 2048);
            }
        }
        #pragma unroll
        for (int ksub = 0; ksub < 2; ++ksub) {
            short8 a[4], b[4];
            #pragma unroll
            for (int mt = 0; mt < 4; ++mt)
                a[mt] = *(const short8*)(&As[cur][0] + (msub + mt * 16 + col) * 64 + ksub * 32 + quad * 8);
            #pragma unroll
            for (int nt = 0; nt < 4; ++nt)
                b[nt] = *(const short8*)(&Bs[cur][0] + (nsub + nt * 16 + col) * 64 + ksub * 32 + quad * 8);
            #pragma unroll
            for (int mt = 0; mt < 4; ++mt)
                #pragma unroll
                for (int nt = 0; nt < 4; ++nt)
                    acc[mt][nt] = __builtin_amdgcn_mfma_f32_16x16x32_bf16(a[mt], b[nt], acc[mt][nt], 0, 0, 0);
        }
    }

    #pragma unroll
    for (int nt = 0; nt < 4; ++nt) {
        float bv = bias[n0 + nsub + nt * 16 + col];
        #pragma unroll
        for (int mt = 0; mt < 4; ++mt) {
            #pragma unroll
            for (int r = 0; r < 4; ++r) {
                int m = m0 + msub + mt * 16 + quad * 4 + r;
                out[(size_t)m * 512 + n0 + nsub + nt * 16 + col] = f2bf(acc[mt][nt][r] + bv);
            }
        }
    }
}

// ---------------- fused attention, two-pass online softmax (unchanged from R3) ----------------
__global__ __launch_bounds__(256) void attn_kernel(
    const short* __restrict__ Q, const short* __restrict__ K, const short* __restrict__ V,
    const float* __restrict__ qmask, const float* __restrict__ kmask,
    const int* __restrict__ caus, float* __restrict__ out, float* __restrict__ aw) {
    __shared__ short vtb[2][64 * 72];
    __shared__ short wl[4 * 16 * 72];    // per-wave w chunk [q][kk]

    int tid = threadIdx.x;
    int lane = tid & 63, wv = tid >> 6;
    int col = lane & 15, quad = lane >> 4;
    int bh = blockIdx.x, qt = blockIdx.y;
    int b = bh >> 3, h = bh & 7;
    int q0 = qt * 64 + wv * 16;
    size_t rowbase = (size_t)b * 512;
    bool causal = (*caus) != 0;
    int lim = causal ? (qt * 4 + wv) : 31;   // wave-uniform last score tile
    int climit = causal ? qt : 7;            // block-uniform last PV chunk

    short8 bQ0, bQ1;
    {
        const short* qp = Q + (rowbase + q0 + col) * 512 + h * 64 + quad * 8;
        bQ0 = *(const short8*)(qp);
        bQ1 = *(const short8*)(qp + 32);
    }

    const short* kp = K + (rowbase + col) * 512 + h * 64 + quad * 8;
    const float* kmp = kmask + b * 512;
    int qg = q0 + col;
    const float C = 0.125f * 1.44269504089f;  // (1/sqrt(64)) * log2(e)

    // ---- pass 1: online (m, l) ----
    float m = -INFINITY, l = 0.f;
    #pragma unroll
    for (int t = 0; t < 32; ++t) {
        if (t <= lim) {
            short8 aK0 = *(const short8*)(kp + (size_t)(t * 16) * 512);
            short8 aK1 = *(const short8*)(kp + (size_t)(t * 16) * 512 + 32);
            float4v s; s[0]=0.f; s[1]=0.f; s[2]=0.f; s[3]=0.f;
            s = __builtin_amdgcn_mfma_f32_16x16x32_bf16(aK0, bQ0, s, 0, 0, 0);
            s = __builtin_amdgcn_mfma_f32_16x16x32_bf16(aK1, bQ1, s, 0, 0, 0);
            int kb = t * 16 + quad * 4;
            float4v km4 = *(const float4v*)(kmp + kb);
            float e0, e1, e2, e3, tmax;
            e0 = ((km4[0] != 0.f) && (!causal || (kb + 0 <= qg))) ? s[0] * C : -INFINITY;
            e1 = ((km4[1] != 0.f) && (!causal || (kb + 1 <= qg))) ? s[1] * C : -INFINITY;
            e2 = ((km4[2] != 0.f) && (!causal || (kb + 2 <= qg))) ? s[2] * C : -INFINITY;
            e3 = ((km4[3] != 0.f) && (!causal || (kb + 3 <= qg))) ? s[3] * C : -INFINITY;
            tmax = fmaxf(fmaxf(e0, e1), fmaxf(e2, e3));
            float nm = fmaxf(m, tmax);
            float f = (m == -INFINITY) ? 0.f : exp2f(m - nm);
            float ls = 0.f;
            ls += (e0 == -INFINITY) ? 0.f : exp2f(e0 - nm);
            ls += (e1 == -INFINITY) ? 0.f : exp2f(e1 - nm);
            ls += (e2 == -INFINITY) ? 0.f : exp2f(e2 - nm);
            ls += (e3 == -INFINITY) ? 0.f : exp2f(e3 - nm);
            l = l * f + ls;
            m = nm;
        }
    }
    #pragma unroll
    for (int off = 16; off <= 32; off <<= 1) {
        float mo = __shfl_xor(m, off, 64);
        float lo = __shfl_xor(l, off, 64);
        float M = fmaxf(m, mo);
        float fa = (m  == -INFINITY) ? 0.f : exp2f(m - M);
        float fb = (mo == -INFINITY) ? 0.f : exp2f(mo - M);
        l = l * fa + lo * fb;
        m = M;
    }
    float qmv = qmask[b * 512 + qg];
    float inv = (l > 0.f) ? (qmv / l) : 0.f;

    // ---- pass 2: recompute, store aw, PV with double-buffered V^T ----
    int kk0 = tid >> 3, sgv = tid & 7;
    const short* vp = V + rowbase * 512 + h * 64 + sgv * 8;
    int lck0 = kk0 ^ (sgv << 3);
    int lck1 = (kk0 + 32) ^ (sgv << 3);
    short8 pva = *(const short8*)(vp + (size_t)(kk0) * 512);
    short8 pvb = *(const short8*)(vp + (size_t)(kk0 + 32) * 512);

    float4v O[4];
    #pragma unroll
    for (int nt = 0; nt < 4; ++nt) { O[nt][0]=0.f; O[nt][1]=0.f; O[nt][2]=0.f; O[nt][3]=0.f; }
    short* wlw = wl + wv * (16 * 72);
    float* awr = aw + ((size_t)b * 8 + h) * 512 * 512 + (size_t)qg * 512 + quad * 4;
    float4v z4; z4[0]=0.f; z4[1]=0.f; z4[2]=0.f; z4[3]=0.f;

    #pragma unroll
    for (int c = 0; c < 8; ++c) {
        if (c <= climit) {   // block-uniform -> barrier-safe
            short* vb = &vtb[c & 1][0];
            #pragma unroll
            for (int j = 0; j < 8; ++j) vb[(sgv * 8 + j) * 72 + lck0] = pva[j];
            #pragma unroll
            for (int j = 0; j < 8; ++j) vb[(sgv * 8 + j) * 72 + lck1] = pvb[j];
            __syncthreads();
            if (c + 1 <= climit) {
                pva = *(const short8*)(vp + (size_t)((c + 1) * 64 + kk0) * 512);
                pvb = *(const short8*)(vp + (size_t)((c + 1) * 64 + kk0 + 32) * 512);
            }
            #pragma unroll
            for (int tl = 0; tl < 4; ++tl) {
                int t = c * 4 + tl;
                short4v w4;
                if (t <= lim) {
                    short8 aK0 = *(const short8*)(kp + (size_t)(t * 16) * 512);
                    short8 aK1 = *(const short8*)(kp + (size_t)(t * 16) * 512 + 32);
                    float4v s; s[0]=0.f; s[1]=0.f; s[2]=0.f; s[3]=0.f;
                    s = __builtin_amdgcn_mfma_f32_16x16x32_bf16(aK0, bQ0, s, 0, 0, 0);
                    s = __builtin_amdgcn_mfma_f32_16x16x32_bf16(aK1, bQ1, s, 0, 0, 0);
                    int kb = t * 16 + quad * 4;
                    float4v km4 = *(const float4v*)(kmp + kb);
                    float4v w;
                    #pragma unroll
                    for (int r = 0; r < 4; ++r) {
                        bool ok = (km4[r] != 0.f) && (!causal || (kb + r <= qg)) && (inv > 0.f);
                        float wvv = ok ? exp2f(s[r] * C - m) * inv : 0.f;
                        w[r] = wvv;
                        w4[r] = f2bf(wvv);
                    }
                    __builtin_nontemporal_store(w, (float4v*)(awr + t * 16));
                } else {
                    w4[0]=0; w4[1]=0; w4[2]=0; w4[3]=0;
                    __builtin_nontemporal_store(z4, (float4v*)(awr + t * 16));
                }
                *(short4v*)(wlw + col * 72 + tl * 16 + quad * 4) = w4;
            }
            #pragma unroll
            for (int sub = 0; sub < 2; ++sub) {
                short8 aW = *(const short8*)(wlw + col * 72 + sub * 32 + quad * 8);
                #pragma unroll
                for (int nt = 0; nt < 4; ++nt) {
                    int d = nt * 16 + col;
                    int cb = (sub * 32 + quad * 8) ^ (((d >> 3) & 7) << 3);
                    short8 bV = *(const short8*)(vb + d * 72 + cb);
                    O[nt] = __builtin_amdgcn_mfma_f32_16x16x32_bf16(aW, bV, O[nt], 0, 0, 0);
                }
            }
        } else {
            #pragma unroll
            for (int tl = 0; tl < 4; ++tl)
                __builtin_nontemporal_store(z4, (float4v*)(awr + (c * 4 + tl) * 16));
        }
    }

    #pragma unroll
    for (int nt = 0; nt < 4; ++nt) {
        #pragma unroll
        for (int r = 0; r < 4; ++r) {
            int qq = q0 + quad * 4 + r;
            __builtin_nontemporal_store(O[nt][r],
                out + (rowbase + qq) * 512 + h * 64 + nt * 16 + col);
        }
    }
}

extern "C" void kernel_launch(void* const* d_in, const int* in_sizes, int n_in,
                              void* d_out, int out_size, void* d_ws, size_t ws_size,
                              hipStream_t stream) {
    const float* queries = (const float*)d_in[0];
    const float* keys    = (const float*)d_in[1];
    const float* Wq      = (const float*)d_in[2];
    const float* bq      = (const float*)d_in[3];
    const float* Wk      = (const float*)d_in[4];
    const float* bk      = (const float*)d_in[5];
    const float* Wv      = (const float*)d_in[6];
    const float* bv      = (const float*)d_in[7];
    const int*   caus    = (const int*)d_in[8];

    const size_t NE = (size_t)16384 * 512;
    short* qbf = (short*)d_ws;
    short* kbf = qbf + NE;
    short* Qb  = kbf + NE;
    short* Kb  = Qb + NE;
    short* Vb  = Kb + NE;
    short* wqb = Vb + NE;
    short* wkb = wqb + 512 * 512;
    short* wvb = wkb + 512 * 512;
    float* qm  = (float*)(wvb + 512 * 512);
    float* km  = qm + 32 * 512;

    cvtmask_kernel<<<8960, 256, 0, stream>>>(queries, keys, qbf, kbf, qm, km,
                                             Wq, Wk, Wv, wqb, wkb, wvb);
    dim3 pg(128, 4, 3);
    proj_kernel<<<pg, 256, 0, stream>>>(qbf, kbf, wqb, wkb, wvb, bq, bk, bv, Qb, Kb, Vb);
    float* outp = (float*)d_out;
    float* awp  = outp + 8388608;
    dim3 ag(256, 8);
    attn_kernel<<<ag, 256, 0, stream>>>(Qb, Kb, Vb, qm, km, caus, outp, awp);
}

// Round 5
// 499.956 us; speedup vs baseline: 1.0191x; 1.0191x over previous
//
#include <hip/hip_runtime.h>
#include <math.h>

typedef short short8 __attribute__((ext_vector_type(8)));
typedef short short4v __attribute__((ext_vector_type(4)));
typedef float float4v __attribute__((ext_vector_type(4)));

// bf16 round-to-nearest-even from fp32, as raw bits in a short
__device__ __forceinline__ short f2bf(float f) {
    union { float f; unsigned u; } v; v.f = f;
    unsigned r = (v.u + 0x7FFFu + ((v.u >> 16) & 1u)) >> 16;
    return (short)r;
}

__device__ __forceinline__ void async16(const short* g, short* l) {
    __builtin_amdgcn_global_load_lds(
        (const __attribute__((address_space(1))) unsigned*)g,
        (__attribute__((address_space(3))) unsigned*)l, 16, 0, 0);
}

// ---------------- fused fp32->bf16 + sign-mask for q/k, PLUS weight cvt ----------------
// blocks [0,8192): q/k rows (4 rows/block). blocks [8192,8960): 3 weight matrices.
__global__ __launch_bounds__(256) void cvtmask_kernel(
    const float* __restrict__ q, const float* __restrict__ k,
    short* __restrict__ qb, short* __restrict__ kb,
    float* __restrict__ qm, float* __restrict__ km,
    const float* __restrict__ w0, const float* __restrict__ w1, const float* __restrict__ w2,
    short* __restrict__ d0, short* __restrict__ d1, short* __restrict__ d2) {
    int tid = threadIdx.x;
    if (blockIdx.x >= 8192) {
        int i = (blockIdx.x - 8192) * 256 + tid;   // 0 .. 3*65536
        int sel = i >> 16;
        int j = i & 65535;
        const float* src = (sel == 0) ? w0 : (sel == 1) ? w1 : w2;
        short* dst       = (sel == 0) ? d0 : (sel == 1) ? d1 : d2;
        float4v v = ((const float4v*)src)[j];
        short4v o;
        o[0] = f2bf(v[0]); o[1] = f2bf(v[1]); o[2] = f2bf(v[2]); o[3] = f2bf(v[3]);
        ((short4v*)dst)[j] = o;
        return;
    }
    int lane = tid & 63, wv = tid >> 6;
    int row = blockIdx.x * 4 + wv;
    const float* src; short* dst; float* msk; int r;
    if (row < 16384) { src = q; dst = qb; msk = qm; r = row; }
    else             { src = k; dst = kb; msk = km; r = row - 16384; }
    const float4v* p = (const float4v*)(src + (size_t)r * 512);
    float4v a = p[lane];
    float4v b = p[lane + 64];
    short4v o1, o2;
    o1[0] = f2bf(a[0]); o1[1] = f2bf(a[1]); o1[2] = f2bf(a[2]); o1[3] = f2bf(a[3]);
    o2[0] = f2bf(b[0]); o2[1] = f2bf(b[1]); o2[2] = f2bf(b[2]); o2[3] = f2bf(b[3]);
    short4v* d4 = (short4v*)(dst + (size_t)r * 512);
    d4[lane] = o1;
    d4[lane + 64] = o2;
    float s = fabsf(a[0]) + fabsf(a[1]) + fabsf(a[2]) + fabsf(a[3])
            + fabsf(b[0]) + fabsf(b[1]) + fabsf(b[2]) + fabsf(b[3]);
    #pragma unroll
    for (int off = 1; off < 64; off <<= 1) s += __shfl_xor(s, off, 64);
    if (lane == 0) msk[r] = (s > 0.f) ? 1.f : 0.f;
}

// ---------------- fused projection GEMM (m97 structure, BK=64, single-buffer) ----------------
// 32 KB LDS -> 3 blocks/CU; implicit wave-level TLP hides staging (m114).
// The 2-phase dbuf variant (64 KB LDS, 2 blocks/CU) measured +8.6us — reverted.
__global__ __launch_bounds__(256) void proj_kernel(
    const short* __restrict__ Xq, const short* __restrict__ Xk,
    const short* __restrict__ Wqp, const short* __restrict__ Wkp, const short* __restrict__ Wvp,
    const float* __restrict__ bqp, const float* __restrict__ bkp, const float* __restrict__ bvp,
    short* __restrict__ Qo, short* __restrict__ Ko, short* __restrict__ Vo) {
    __shared__ short As[128 * 64];
    __shared__ short Bs[128 * 64];
    int z = blockIdx.z;
    const short* X    = (z == 0) ? Xq  : Xk;
    const short* W    = (z == 0) ? Wqp : (z == 1) ? Wkp : Wvp;
    const float* bias = (z == 0) ? bqp : (z == 1) ? bkp : bvp;
    short* out        = (z == 0) ? Qo  : (z == 1) ? Ko  : Vo;

    int tid = threadIdx.x;
    int lane = tid & 63, wv = tid >> 6;
    int col = lane & 15, quad = lane >> 4;
    int m0 = blockIdx.x * 128;
    int n0 = blockIdx.y * 128;
    int msub = (wv & 1) * 64, nsub = (wv >> 1) * 64;

    float4v acc[4][4];
    #pragma unroll
    for (int mt = 0; mt < 4; ++mt)
        #pragma unroll
        for (int nt = 0; nt < 4; ++nt) { acc[mt][nt][0]=0.f; acc[mt][nt][1]=0.f; acc[mt][nt][2]=0.f; acc[mt][nt][3]=0.f; }

    int rowS = tid >> 3;   // 0..31
    int seg  = tid & 7;    // 16B segment within a 128B row
    const short* gA = X + (size_t)(m0 + rowS) * 512 + seg * 8;
    const short* gB = W + (size_t)(n0 + rowS) * 512 + seg * 8;
    short* lA = As + (size_t)tid * 8;
    short* lB = Bs + (size_t)tid * 8;

    for (int k0 = 0; k0 < 512; k0 += 64) {
        __syncthreads();
        #pragma unroll
        for (int j = 0; j < 4; ++j) {
            async16(gA + (size_t)(j * 32) * 512 + k0, lA + j * 2048);
            async16(gB + (size_t)(j * 32) * 512 + k0, lB + j * 2048);
        }
        __syncthreads();
        #pragma unroll
        for (int ksub = 0; ksub < 2; ++ksub) {
            short8 a[4], b[4];
            #pragma unroll
            for (int mt = 0; mt < 4; ++mt)
                a[mt] = *(const short8*)(As + (msub + mt * 16 + col) * 64 + ksub * 32 + quad * 8);
            #pragma unroll
            for (int nt = 0; nt < 4; ++nt)
                b[nt] = *(const short8*)(Bs + (nsub + nt * 16 + col) * 64 + ksub * 32 + quad * 8);
            #pragma unroll
            for (int mt = 0; mt < 4; ++mt)
                #pragma unroll
                for (int nt = 0; nt < 4; ++nt)
                    acc[mt][nt] = __builtin_amdgcn_mfma_f32_16x16x32_bf16(a[mt], b[nt], acc[mt][nt], 0, 0, 0);
        }
    }

    #pragma unroll
    for (int nt = 0; nt < 4; ++nt) {
        float bv = bias[n0 + nsub + nt * 16 + col];
        #pragma unroll
        for (int mt = 0; mt < 4; ++mt) {
            #pragma unroll
            for (int r = 0; r < 4; ++r) {
                int m = m0 + msub + mt * 16 + quad * 4 + r;
                out[(size_t)m * 512 + n0 + nsub + nt * 16 + col] = f2bf(acc[mt][nt][r] + bv);
            }
        }
    }
}

// ---------------- fused attention, two-pass online softmax (R3 best) ----------------
__global__ __launch_bounds__(256) void attn_kernel(
    const short* __restrict__ Q, const short* __restrict__ K, const short* __restrict__ V,
    const float* __restrict__ qmask, const float* __restrict__ kmask,
    const int* __restrict__ caus, float* __restrict__ out, float* __restrict__ aw) {
    __shared__ short vtb[2][64 * 72];
    __shared__ short wl[4 * 16 * 72];    // per-wave w chunk [q][kk]

    int tid = threadIdx.x;
    int lane = tid & 63, wv = tid >> 6;
    int col = lane & 15, quad = lane >> 4;
    int bh = blockIdx.x, qt = blockIdx.y;
    int b = bh >> 3, h = bh & 7;
    int q0 = qt * 64 + wv * 16;
    size_t rowbase = (size_t)b * 512;
    bool causal = (*caus) != 0;
    int lim = causal ? (qt * 4 + wv) : 31;   // wave-uniform last score tile
    int climit = causal ? qt : 7;            // block-uniform last PV chunk

    short8 bQ0, bQ1;
    {
        const short* qp = Q + (rowbase + q0 + col) * 512 + h * 64 + quad * 8;
        bQ0 = *(const short8*)(qp);
        bQ1 = *(const short8*)(qp + 32);
    }

    const short* kp = K + (rowbase + col) * 512 + h * 64 + quad * 8;
    const float* kmp = kmask + b * 512;
    int qg = q0 + col;
    const float C = 0.125f * 1.44269504089f;  // (1/sqrt(64)) * log2(e)

    // ---- pass 1: online (m, l) ----
    float m = -INFINITY, l = 0.f;
    #pragma unroll
    for (int t = 0; t < 32; ++t) {
        if (t <= lim) {
            short8 aK0 = *(const short8*)(kp + (size_t)(t * 16) * 512);
            short8 aK1 = *(const short8*)(kp + (size_t)(t * 16) * 512 + 32);
            float4v s; s[0]=0.f; s[1]=0.f; s[2]=0.f; s[3]=0.f;
            s = __builtin_amdgcn_mfma_f32_16x16x32_bf16(aK0, bQ0, s, 0, 0, 0);
            s = __builtin_amdgcn_mfma_f32_16x16x32_bf16(aK1, bQ1, s, 0, 0, 0);
            int kb = t * 16 + quad * 4;
            float4v km4 = *(const float4v*)(kmp + kb);
            float e0, e1, e2, e3, tmax;
            e0 = ((km4[0] != 0.f) && (!causal || (kb + 0 <= qg))) ? s[0] * C : -INFINITY;
            e1 = ((km4[1] != 0.f) && (!causal || (kb + 1 <= qg))) ? s[1] * C : -INFINITY;
            e2 = ((km4[2] != 0.f) && (!causal || (kb + 2 <= qg))) ? s[2] * C : -INFINITY;
            e3 = ((km4[3] != 0.f) && (!causal || (kb + 3 <= qg))) ? s[3] * C : -INFINITY;
            tmax = fmaxf(fmaxf(e0, e1), fmaxf(e2, e3));
            float nm = fmaxf(m, tmax);
            float f = (m == -INFINITY) ? 0.f : exp2f(m - nm);
            float ls = 0.f;
            ls += (e0 == -INFINITY) ? 0.f : exp2f(e0 - nm);
            ls += (e1 == -INFINITY) ? 0.f : exp2f(e1 - nm);
            ls += (e2 == -INFINITY) ? 0.f : exp2f(e2 - nm);
            ls += (e3 == -INFINITY) ? 0.f : exp2f(e3 - nm);
            l = l * f + ls;
            m = nm;
        }
    }
    #pragma unroll
    for (int off = 16; off <= 32; off <<= 1) {
        float mo = __shfl_xor(m, off, 64);
        float lo = __shfl_xor(l, off, 64);
        float M = fmaxf(m, mo);
        float fa = (m  == -INFINITY) ? 0.f : exp2f(m - M);
        float fb = (mo == -INFINITY) ? 0.f : exp2f(mo - M);
        l = l * fa + lo * fb;
        m = M;
    }
    float qmv = qmask[b * 512 + qg];
    float inv = (l > 0.f) ? (qmv / l) : 0.f;

    // ---- pass 2: recompute, store aw, PV with double-buffered V^T ----
    int kk0 = tid >> 3, sgv = tid & 7;
    const short* vp = V + rowbase * 512 + h * 64 + sgv * 8;
    int lck0 = kk0 ^ (sgv << 3);
    int lck1 = (kk0 + 32) ^ (sgv << 3);
    short8 pva = *(const short8*)(vp + (size_t)(kk0) * 512);
    short8 pvb = *(const short8*)(vp + (size_t)(kk0 + 32) * 512);

    float4v O[4];
    #pragma unroll
    for (int nt = 0; nt < 4; ++nt) { O[nt][0]=0.f; O[nt][1]=0.f; O[nt][2]=0.f; O[nt][3]=0.f; }
    short* wlw = wl + wv * (16 * 72);
    float* awr = aw + ((size_t)b * 8 + h) * 512 * 512 + (size_t)qg * 512 + quad * 4;
    float4v z4; z4[0]=0.f; z4[1]=0.f; z4[2]=0.f; z4[3]=0.f;

    #pragma unroll
    for (int c = 0; c < 8; ++c) {
        if (c <= climit) {   // block-uniform -> barrier-safe
            short* vb = &vtb[c & 1][0];
            #pragma unroll
            for (int j = 0; j < 8; ++j) vb[(sgv * 8 + j) * 72 + lck0] = pva[j];
            #pragma unroll
            for (int j = 0; j < 8; ++j) vb[(sgv * 8 + j) * 72 + lck1] = pvb[j];
            __syncthreads();
            if (c + 1 <= climit) {
                pva = *(const short8*)(vp + (size_t)((c + 1) * 64 + kk0) * 512);
                pvb = *(const short8*)(vp + (size_t)((c + 1) * 64 + kk0 + 32) * 512);
            }
            #pragma unroll
            for (int tl = 0; tl < 4; ++tl) {
                int t = c * 4 + tl;
                short4v w4;
                if (t <= lim) {
                    short8 aK0 = *(const short8*)(kp + (size_t)(t * 16) * 512);
                    short8 aK1 = *(const short8*)(kp + (size_t)(t * 16) * 512 + 32);
                    float4v s; s[0]=0.f; s[1]=0.f; s[2]=0.f; s[3]=0.f;
                    s = __builtin_amdgcn_mfma_f32_16x16x32_bf16(aK0, bQ0, s, 0, 0, 0);
                    s = __builtin_amdgcn_mfma_f32_16x16x32_bf16(aK1, bQ1, s, 0, 0, 0);
                    int kb = t * 16 + quad * 4;
                    float4v km4 = *(const float4v*)(kmp + kb);
                    float4v w;
                    #pragma unroll
                    for (int r = 0; r < 4; ++r) {
                        bool ok = (km4[r] != 0.f) && (!causal || (kb + r <= qg)) && (inv > 0.f);
                        float wvv = ok ? exp2f(s[r] * C - m) * inv : 0.f;
                        w[r] = wvv;
                        w4[r] = f2bf(wvv);
                    }
                    __builtin_nontemporal_store(w, (float4v*)(awr + t * 16));
                } else {
                    w4[0]=0; w4[1]=0; w4[2]=0; w4[3]=0;
                    __builtin_nontemporal_store(z4, (float4v*)(awr + t * 16));
                }
                *(short4v*)(wlw + col * 72 + tl * 16 + quad * 4) = w4;
            }
            #pragma unroll
            for (int sub = 0; sub < 2; ++sub) {
                short8 aW = *(const short8*)(wlw + col * 72 + sub * 32 + quad * 8);
                #pragma unroll
                for (int nt = 0; nt < 4; ++nt) {
                    int d = nt * 16 + col;
                    int cb = (sub * 32 + quad * 8) ^ (((d >> 3) & 7) << 3);
                    short8 bV = *(const short8*)(vb + d * 72 + cb);
                    O[nt] = __builtin_amdgcn_mfma_f32_16x16x32_bf16(aW, bV, O[nt], 0, 0, 0);
                }
            }
        } else {
            #pragma unroll
            for (int tl = 0; tl < 4; ++tl)
                __builtin_nontemporal_store(z4, (float4v*)(awr + (c * 4 + tl) * 16));
        }
    }

    #pragma unroll
    for (int nt = 0; nt < 4; ++nt) {
        #pragma unroll
        for (int r = 0; r < 4; ++r) {
            int qq = q0 + quad * 4 + r;
            __builtin_nontemporal_store(O[nt][r],
                out + (rowbase + qq) * 512 + h * 64 + nt * 16 + col);
        }
    }
}

extern "C" void kernel_launch(void* const* d_in, const int* in_sizes, int n_in,
                              void* d_out, int out_size, void* d_ws, size_t ws_size,
                              hipStream_t stream) {
    const float* queries = (const float*)d_in[0];
    const float* keys    = (const float*)d_in[1];
    const float* Wq      = (const float*)d_in[2];
    const float* bq      = (const float*)d_in[3];
    const float* Wk      = (const float*)d_in[4];
    const float* bk      = (const float*)d_in[5];
    const float* Wv      = (const float*)d_in[6];
    const float* bv      = (const float*)d_in[7];
    const int*   caus    = (const int*)d_in[8];

    const size_t NE = (size_t)16384 * 512;
    short* qbf = (short*)d_ws;
    short* kbf = qbf + NE;
    short* Qb  = kbf + NE;
    short* Kb  = Qb + NE;
    short* Vb  = Kb + NE;
    short* wqb = Vb + NE;
    short* wkb = wqb + 512 * 512;
    short* wvb = wkb + 512 * 512;
    float* qm  = (float*)(wvb + 512 * 512);
    float* km  = qm + 32 * 512;

    cvtmask_kernel<<<8960, 256, 0, stream>>>(queries, keys, qbf, kbf, qm, km,
                                             Wq, Wk, Wv, wqb, wkb, wvb);
    dim3 pg(128, 4, 3);
    proj_kernel<<<pg, 256, 0, stream>>>(qbf, kbf, wqb, wkb, wvb, bq, bk, bv, Qb, Kb, Vb);
    float* outp = (float*)d_out;
    float* awp  = outp + 8388608;
    dim3 ag(256, 8);
    attn_kernel<<<ag, 256, 0, stream>>>(Qb, Kb, Vb, qm, km, caus, outp, awp);
}